// Round 14
// baseline (90.100 us; speedup 1.0000x reference)
//
#include <hip/hip_runtime.h>
#include <stdint.h>

// BinarizeLinear: out[i][j] = sum_k sign(x[i][k]) * sign(W[j][k]) + bias[j]
// R14 = R13 (MX-FP4, exact +-1) with a BIGGER PER-WAVE TILE: 128x64 out/wave
// (fr=8), block tile 256x256, BK=128 fp4 (64 B rows). Rationale: per-wave LDS
// fragment traffic is set by the wave tile, not the schedule (R3/R10/R11/R12
// all converged at 83 µs); at 64x64 LDS-port time (1130 cyc/CU/iter) exceeded
// fp4 MFMA time (713); at 128x64 MFMA (1425) > LDS (1130) -> compute-bound.
// Regs: acc 128 (AGPR) + a 32 + b8 32 + temps ~240 < 256 (1 block/CU).
// Schedule/swizzle/stage = R11/R13 race-verified pattern unchanged:
// reads -> lgkm(0) -> BAR -> STAGE(cur,t+2) -> MFMA -> vmcnt(4) -> BAR.
// Exact: fp4 e2m1 +-1 (0x2/0xA), scale E8M0 0x7F=1.0, f32 accum, sums <= 2048.

#define Mdim 16384
#define Ndim 2048
#define Kdim 2048
#define NT 16  // K-tiles of 128 fp4 (64 B)

using i32x4 = __attribute__((ext_vector_type(4))) int;
using i32x8 = __attribute__((ext_vector_type(8))) int;
using f32x4 = __attribute__((ext_vector_type(4))) float;

// Binarize f32 -> packed fp4 (+1=0x2, -1=0xA), 16 f32 -> 8 bytes per thread.
__global__ __launch_bounds__(256) void binarize_fp4(const float* __restrict__ x,
                                                    const float* __restrict__ w,
                                                    uint8_t* __restrict__ out,
                                                    int nx16, int ntot16) {
  int i = blockIdx.x * 256 + threadIdx.x;
  if (i >= ntot16) return;
  const float4* p = (i < nx16) ? ((const float4*)x + (size_t)i * 4)
                               : ((const float4*)w + (size_t)(i - nx16) * 4);
  float4 f0 = p[0], f1 = p[1], f2 = p[2], f3 = p[3];
  float s[16] = {f0.x, f0.y, f0.z, f0.w, f1.x, f1.y, f1.z, f1.w,
                 f2.x, f2.y, f2.z, f2.w, f3.x, f3.y, f3.z, f3.w};
  union { uint8_t b[8]; uint2 v; } u;
#pragma unroll
  for (int j = 0; j < 8; ++j) {
    const unsigned lo = s[2 * j] > 0.0f ? 0x2u : 0xAu;
    const unsigned hi = s[2 * j + 1] > 0.0f ? 0x2u : 0xAu;
    u.b[j] = (uint8_t)(lo | (hi << 4));
  }
  ((uint2*)out)[i] = u.v;  // xb4 then wb4, contiguous
}

__device__ __forceinline__ void gl_lds16(const void* gsrc, void* ldst) {
  __builtin_amdgcn_global_load_lds(
      (const __attribute__((address_space(1))) void*)gsrc,
      (__attribute__((address_space(3))) void*)ldst, 16, 0, 0);
}

__device__ __forceinline__ i32x8 dup8(i32x4 v) {
  i32x8 r;
  r[0] = v[0]; r[1] = v[1]; r[2] = v[2]; r[3] = v[3];
  r[4] = v[0]; r[5] = v[1]; r[6] = v[2]; r[7] = v[3];  // fp4 uses regs [0:3]
  return r;
}

__global__ __launch_bounds__(512, 1) void bin_gemm_fp4(const uint8_t* __restrict__ A4,
                                                       const uint8_t* __restrict__ W4,
                                                       const float* __restrict__ bias,
                                                       float* __restrict__ C) {
  // Row = 64 B = 128 fp4 of one K-tile. A: [2][256 rows], B: [2][256 rows]. 64 KB.
  __shared__ __align__(16) uint8_t As[2][256 * 64];
  __shared__ __align__(16) uint8_t Bs[2][256 * 64];

  const int tid = threadIdx.x;
  const int lane = tid & 63;
  const int wid = tid >> 6;  // 0..7
  const int wm = wid >> 2;   // 0..1 (M half: 128 rows)
  const int wn = wid & 3;    // 0..3 (N quarter: 64 cols)

  // XCD swizzle: 512 blocks, %8==0 -> bijective; consecutive swz per XCD sweep
  // bcol fastest -> the 8 A-panel sharers are co-XCD (L2 reuse).
  const int bid = blockIdx.x;
  const int swz = (bid & 7) * 64 + (bid >> 3);
  const long brow = (long)(swz >> 3) * 256;  // 64 M-panels
  const long bcol = (long)(swz & 7) * 256;   // 8 col-tiles

  // ---- staging: linear LDS dest; swizzle on global SOURCE slot.
  // 16 rows per gl_lds (4 lanes x 16 B per 64 B row); f(row)=(row>>1)&3 with
  // row = 16k + lane>>2 -> f = (lane>>3)&3 (wave-uniform per-lane form).
  const int slin = lane & 3;
  const int sgcol = (slin ^ ((lane >> 3) & 3)) * 16;
  const int srAB = wid * 32 + (lane >> 2);  // rows, 2 gl_lds per operand (+0,+16)

  // ---- fragment ds_read offsets (swizzled: slot ^ ((row>>1)&3)) ----
  int offA[8], offB[4];
#pragma unroll
  for (int fr = 0; fr < 8; ++fr) {
    const int ra = wm * 128 + fr * 16 + (lane & 15);
    const int s = lane >> 4;
    offA[fr] = ra * 64 + ((s ^ ((ra >> 1) & 3)) * 16);
  }
#pragma unroll
  for (int fc = 0; fc < 4; ++fc) {
    const int rb = wn * 64 + fc * 16 + (lane & 15);
    const int s = lane >> 4;
    offB[fc] = rb * 64 + ((s ^ ((rb >> 1) & 3)) * 16);
  }

  f32x4 acc[8][4] = {};  // 128 accumulator regs (AGPR side)
  i32x4 a[8];
  i32x8 b8[4];

  const long rowBytes = Kdim / 2;  // 1024 B per logical row

#define BAR() asm volatile("s_barrier" ::: "memory")
#define STAGE(BUF, KT)                                                                  \
  do {                                                                                  \
    const uint8_t* sa_ = A4 + (brow + srAB) * rowBytes + ((long)(KT) << 6) + sgcol;     \
    gl_lds16(sa_, &As[BUF][wid * 2048]);                                                \
    gl_lds16(sa_ + 16 * rowBytes, &As[BUF][wid * 2048 + 1024]);                         \
    const uint8_t* sb_ = W4 + (bcol + srAB) * rowBytes + ((long)(KT) << 6) + sgcol;     \
    gl_lds16(sb_, &Bs[BUF][wid * 2048]);                                                \
    gl_lds16(sb_ + 16 * rowBytes, &Bs[BUF][wid * 2048 + 1024]);                         \
  } while (0)

  // ---- prologue: stage tiles 0,1 (4 gl_lds/wave each); tile0 resident.
  STAGE(0, 0);
  STAGE(1, 1);
  asm volatile("s_waitcnt vmcnt(4)" ::: "memory");
  BAR();

#pragma unroll 1
  for (int t = 0; t < NT; ++t) {
    const int cur = t & 1;

    // reads of buf cur (12 x ds_read_b128), drained before the barrier
#pragma unroll
    for (int fr = 0; fr < 8; ++fr) a[fr] = *(const i32x4*)&As[cur][offA[fr]];
#pragma unroll
    for (int fc = 0; fc < 4; ++fc) b8[fc] = dup8(*(const i32x4*)&Bs[cur][offB[fc]]);
    asm volatile("s_waitcnt lgkmcnt(0)" ::: "memory");
    BAR();  // all waves done reading buf cur

    // overwrite cur with tile t+2 (post-barrier: safe)
    if (t + 2 < NT) STAGE(cur, t + 2);

    __builtin_amdgcn_s_setprio(1);
#pragma unroll
    for (int fr = 0; fr < 8; ++fr) {
      const i32x8 a8 = dup8(a[fr]);
#pragma unroll
      for (int fc = 0; fc < 4; ++fc) {
        // cbsz=4 (A=fp4), blgp=4 (B=fp4); scales E8M0 0x7F = 1.0 (exact).
        acc[fr][fc] = __builtin_amdgcn_mfma_scale_f32_16x16x128_f8f6f4(
            a8, b8[fc], acc[fr][fc], 4, 4, 0, 0x7F7F7F7F, 0, 0x7F7F7F7F);
      }
    }
    __builtin_amdgcn_s_setprio(0);

    // retire tile t+1's stages (4 newest = tile t+2's, just issued)
    if (t < NT - 2) {
      asm volatile("s_waitcnt vmcnt(4)" ::: "memory");
    } else {
      asm volatile("s_waitcnt vmcnt(0)" ::: "memory");
    }
    BAR();
  }

  // ---- epilogue: C/D layout col=lane&15, row=(lane>>4)*4+reg ----
#pragma unroll
  for (int fc = 0; fc < 4; ++fc) {
    const long col = bcol + wn * 64 + fc * 16 + (lane & 15);
    const float bj = bias[col];
#pragma unroll
    for (int fr = 0; fr < 8; ++fr) {
      const long row0 = brow + wm * 128 + fr * 16 + (lane >> 4) * 4;
#pragma unroll
      for (int r = 0; r < 4; ++r) {
        C[(row0 + r) * (long)Ndim + col] = acc[fr][fc][r] + bj;
      }
    }
  }
#undef BAR
#undef STAGE
}

extern "C" void kernel_launch(void* const* d_in, const int* in_sizes, int n_in,
                              void* d_out, int out_size, void* d_ws, size_t ws_size,
                              hipStream_t stream) {
  const float* x = (const float*)d_in[0];
  const float* w = (const float*)d_in[1];
  const float* bias = (const float*)d_in[2];
  float* out = (float*)d_out;

  uint8_t* xb4 = (uint8_t*)d_ws;                 // 16.8 MB (fp4-packed)
  uint8_t* wb4 = xb4 + (size_t)Mdim * Kdim / 2;  // + 2.1 MB (ws >= 18.9 MB)

  const int nx16 = Mdim * Kdim / 16;  // 16-f32 units
  const int nw16 = Ndim * Kdim / 16;
  const int ntot16 = nx16 + nw16;
  binarize_fp4<<<(ntot16 + 255) / 256, 256, 0, stream>>>(x, w, xb4, nx16, ntot16);

  dim3 grid((Mdim / 256) * (Ndim / 256));  // 512 blocks, %8==0
  bin_gemm_fp4<<<grid, 512, 0, stream>>>(xb4, wb4, bias, out);
}